// Round 8
// baseline (329.465 us; speedup 1.0000x reference)
//
#include <hip/hip_runtime.h>
#include <hip/hip_cooperative_groups.h>
#include <cmath>

namespace cg = cooperative_groups;

#define A_CNT 196416
#define C_CNT 90
#define PAIRS (A_CNT / 2)            // 98208 pairs; 12276 wave-iters x 8 pairs
#define WITERS 12276
#define TOPK 100u
#define CAPB 2048
#define NBLK 1024                    // 4 blocks/CU co-resident (22.7 KB LDS, <=128 VGPR)
#define NWAVE (NBLK * 4)             // 4096 waves; 3 iters/wave covers 12288 >= 12276

// ws layout (bytes):
//   [0, 4096)        hist1[1024] (coarse: idx 0 = zero-key, 1..565 = top16-0x3D4B)
//   [4096, 4160)     ctrl[16]: 5=candA_cnt 6=candB_cnt
//   [4160, 4672)     cAi[128]   candidate-A anchor idx (strictly above binB; count = G < 100)
//   [4672, 5184)     cAk[128]   candidate-A keys
//   [5184, 13376)    cBi[2048]  candidate-B anchor idx (top16 == binB)
//   [13376, 21568)   cBk[2048]  candidate-B keys
#define OFF_CTRL 4096u
#define OFF_CAI  4160u
#define OFF_CAK  4672u
#define OFF_CBI  5184u
#define OFF_CBK  13376u

#define AGENT_LD(p)    __hip_atomic_load((p), __ATOMIC_RELAXED, __HIP_MEMORY_SCOPE_AGENT)
#define AGENT_ST(p, v) __hip_atomic_store((p), (v), __ATOMIC_RELAXED, __HIP_MEMORY_SCOPE_AGENT)

// Single cooperative kernel:
//  P1: 8-lane-coop max reduce (R5 structure, best observed), keys kept in LDS.
//  sync; P2: every block redundantly suffix-scans the 4 KB histogram -> binB.
//  P3: each block classifies its own 192 LDS (key,anchor) entries -> global cand lists.
//  sync; P4: block 0 ranks candidates (key desc, idx asc = lax.top_k stable order),
//  argmaxes raw logits (sigmoid monotonic), decodes+clips boxes, writes 600 f32.
__global__ __launch_bounds__(256, 4) void k_all(const float* __restrict__ cls,
                                                const float* __restrict__ reg,
                                                const float* __restrict__ anc,
                                                unsigned* __restrict__ hist1,
                                                unsigned* __restrict__ ctrl,
                                                unsigned* __restrict__ cAi,
                                                unsigned* __restrict__ cAk,
                                                unsigned* __restrict__ cBi,
                                                unsigned* __restrict__ cBk,
                                                float* __restrict__ out) {
    __shared__ unsigned lhist[576];
    __shared__ unsigned skey[192], sanchor[192];     // 4 waves x 3 iters x 16 anchors
    __shared__ unsigned sdata[256], sres[2];
    __shared__ unsigned sAi[128], sAk[128];
    __shared__ unsigned sBi[CAPB], sBk[CAPB];
    __shared__ unsigned selI[TOPK], selK[TOPK];

    const int t = threadIdx.x;
    for (int j = t; j < 576; j += 256) lhist[j] = 0u;
    if (t < 192) sanchor[t] = 0xFFFFFFFFu;           // sentinel: slot unused
    __syncthreads();

    // ---- P1: reduce ----
    const int lane = t & 63;
    const int g = lane >> 3, s = lane & 7;
    const int wl = t >> 6;                           // wave-in-block
    const int W = blockIdx.x * 4 + wl;               // global wave id
    const float4* __restrict__ cls4 = (const float4*)cls;

#pragma unroll
    for (int it = 0; it < 3; ++it) {
        const int w = W + it * NWAVE;
        if (w < WITERS) {
            const int p = w * 8 + g;                 // pair index < PAIRS
            const float4* __restrict__ r4 = cls4 + (size_t)p * 45;
            float m0 = -INFINITY, m1 = -INFINITY;
#pragma unroll
            for (int i = 0; i < 6; ++i) {
                const int j = s + 8 * i;             // 45 chunks: s<5 -> 6, s>=5 -> 5
                if (j < 45) {
                    float4 v = r4[j];
                    float a01 = fmaxf(v.x, v.y), a23 = fmaxf(v.z, v.w);
                    float all = fmaxf(a01, a23);
                    if (j < 22)      m0 = fmaxf(m0, all);
                    else if (j > 22) m1 = fmaxf(m1, all);
                    else { m0 = fmaxf(m0, a01); m1 = fmaxf(m1, a23); }  // 88,89|90,91
                }
            }
#pragma unroll
            for (int d = 1; d < 8; d <<= 1) {        // 8-lane group reduce
                m0 = fmaxf(m0, __shfl_xor(m0, d));
                m1 = fmaxf(m1, __shfl_xor(m1, d));
            }
            if (s == 0) {
                float p0 = 1.0f / (1.0f + expf(-m0));    // sigmoid(max)==max(sigmoid)
                float p1 = 1.0f / (1.0f + expf(-m1));
                unsigned k0 = (p0 > 0.05f) ? __float_as_uint(p0) : 0u;
                unsigned k1 = (p1 > 0.05f) ? __float_as_uint(p1) : 0u;
                const int sb = wl * 48 + it * 16 + g * 2;
                skey[sb] = k0;     skey[sb + 1] = k1;
                sanchor[sb] = 2u * p; sanchor[sb + 1] = 2u * p + 1u;
                unsigned h0 = k0 ? (min(k0 >> 16, 0x3F80u) - 0x3D4Bu) : 0u;  // 0=zeros,1..565
                unsigned h1 = k1 ? (min(k1 >> 16, 0x3F80u) - 0x3D4Bu) : 0u;
                atomicAdd(&lhist[h0], 1u);
                atomicAdd(&lhist[h1], 1u);
            }
        }
    }
    __syncthreads();
    for (int j = t; j < 576; j += 256) {
        unsigned c = lhist[j];
        if (c) atomicAdd(&hist1[j], c);              // device-scope by default
    }

    cg::this_grid().sync();

    // ---- P2: every block computes binB from the global histogram ----
    {
        unsigned ssum = 0;
#pragma unroll
        for (int j = 0; j < 4; ++j) ssum += AGENT_LD(&hist1[t * 4 + j]);
        sdata[t] = ssum;
        for (int d = 1; d < 256; d <<= 1) {          // Hillis-Steele inclusive suffix scan
            __syncthreads();
            unsigned add = (t + d < 256) ? sdata[t + d] : 0u;
            __syncthreads();
            sdata[t] += add;
        }
        __syncthreads();
        {
            unsigned mysuf  = sdata[t];
            unsigned nxtsuf = (t < 255) ? sdata[t + 1] : 0u;
            if (nxtsuf < TOPK && mysuf >= TOPK) { sres[0] = (unsigned)t; sres[1] = nxtsuf; }
        }
        __syncthreads();
        const unsigned chunkB = sres[0];
        const unsigned gAbove = sres[1];
        unsigned v = (t < 4) ? AGENT_LD(&hist1[chunkB * 4 + t]) : 0u;
        sdata[t] = v;
        for (int d = 1; d < 256; d <<= 1) {
            __syncthreads();
            unsigned add = (t + d < 256) ? sdata[t + d] : 0u;
            __syncthreads();
            sdata[t] += add;
        }
        __syncthreads();
        {
            unsigned mysuf  = sdata[t] + gAbove;
            unsigned nxtsuf = ((t < 255) ? sdata[t + 1] : 0u) + gAbove;
            if (nxtsuf < TOPK && mysuf >= TOPK) {
                unsigned bin = chunkB * 4 + (unsigned)t;   // 0=zeros, 1..565
                sres[0] = bin ? (bin + 0x3D4Bu) : 0u;      // true top-16 bits
            }
        }
        __syncthreads();
    }
    const unsigned binB = sres[0];

    // ---- P3: gather this block's own entries ----
    if (t < 192) {
        unsigned a = sanchor[t];
        if (a != 0xFFFFFFFFu) {
            unsigned kk = skey[t], t16 = kk >> 16;
            if (t16 > binB) {
                unsigned q = atomicAdd(&ctrl[5], 1u);
                if (q < 128u) { AGENT_ST(&cAi[q], a); AGENT_ST(&cAk[q], kk); }
            } else if (t16 == binB) {
                unsigned q = atomicAdd(&ctrl[6], 1u);
                if (q < (unsigned)CAPB) { AGENT_ST(&cBi[q], a); AGENT_ST(&cBk[q], kk); }
            }
        }
    }

    cg::this_grid().sync();

    // ---- P4: block 0 ranks + decodes ----
    if (blockIdx.x != 0) return;
    const unsigned nA = min(AGENT_LD(&ctrl[5]), 128u);       // exact G < 100
    const unsigned nB = min(AGENT_LD(&ctrl[6]), (unsigned)CAPB);
    const unsigned need = (nA < TOPK) ? (TOPK - nA) : 0u;    // in-bin count >= need

    if (t < (int)nA) { sAi[t] = AGENT_LD(&cAi[t]); sAk[t] = AGENT_LD(&cAk[t]); }
    for (unsigned e = (unsigned)t; e < nB; e += 256u) {
        sBi[e] = AGENT_LD(&cBi[e]); sBk[e] = AGENT_LD(&cBk[e]);
    }
    __syncthreads();

    if (t < (int)nA) {                               // rank strictly-above candidates
        unsigned mi = sAi[t], mk = sAk[t], r = 0;
        for (unsigned j = 0; j < nA; ++j) {
            unsigned ok = sAk[j];
            if (ok > mk || (ok == mk && sAi[j] < mi)) r++;
        }
        selI[r] = mi; selK[r] = mk;
    }
    for (unsigned e = (unsigned)t; e < nB; e += 256u) {  // in-bin: (key desc, idx asc)
        unsigned mi = sBi[e], mk = sBk[e], r = 0;
        for (unsigned j = 0; j < nB; ++j) {
            unsigned ok = sBk[j];
            if (ok > mk || (ok == mk && sBi[j] < mi)) r++;
        }
        if (r < need) { selI[nA + r] = mi; selK[nA + r] = mk; }
    }
    __syncthreads();

    if (t < (int)TOPK) {
        const unsigned a = selI[t];
        const float2* row = (const float2*)(cls + (size_t)a * C_CNT);
        float bv = -INFINITY; int bi = 0;
#pragma unroll 5
        for (int c = 0; c < 45; ++c) {               // argmax over RAW logits
            float2 v = row[c];                       // strict > = first-index tie
            if (v.x > bv) { bv = v.x; bi = 2 * c; }
            if (v.y > bv) { bv = v.y; bi = 2 * c + 1; }
        }
        float score = __uint_as_float(selK[t]);      // prob bits, or 0.0 if thresholded
        float x1a = anc[a * 4 + 0], y1a = anc[a * 4 + 1];
        float x2a = anc[a * 4 + 2], y2a = anc[a * 4 + 3];
        float wa = x2a - x1a, ha = y2a - y1a;
        float cxa = x1a + 0.5f * wa, cya = y1a + 0.5f * ha;
        float dx = reg[a * 4 + 0] * 0.1f, dy = reg[a * 4 + 1] * 0.1f;
        float dw = reg[a * 4 + 2] * 0.2f, dh = reg[a * 4 + 3] * 0.2f;
        float cx = cxa + dx * wa, cy = cya + dy * ha;
        float w = expf(dw) * wa, h = expf(dh) * ha;
        out[t * 4 + 0] = fmaxf(cx - 0.5f * w, 0.0f);
        out[t * 4 + 1] = fmaxf(cy - 0.5f * h, 0.0f);
        out[t * 4 + 2] = fminf(cx + 0.5f * w, 1024.0f);
        out[t * 4 + 3] = fminf(cy + 0.5f * h, 1024.0f);
        out[400 + t] = score;
        out[500 + t] = (float)bi;
    }
}

extern "C" void kernel_launch(void* const* d_in, const int* in_sizes, int n_in,
                              void* d_out, int out_size, void* d_ws, size_t ws_size,
                              hipStream_t stream) {
    const float* reg = (const float*)d_in[1];
    const float* cls = (const float*)d_in[2];
    const float* anc = (const float*)d_in[3];
    float* out = (float*)d_out;
    char* ws = (char*)d_ws;
    unsigned* hist1 = (unsigned*)ws;
    unsigned* ctrl  = (unsigned*)(ws + OFF_CTRL);
    unsigned* cAi   = (unsigned*)(ws + OFF_CAI);
    unsigned* cAk   = (unsigned*)(ws + OFF_CAK);
    unsigned* cBi   = (unsigned*)(ws + OFF_CBI);
    unsigned* cBk   = (unsigned*)(ws + OFF_CBK);

    hipMemsetAsync(hist1, 0, 4096 + 64, stream);     // hist1 + ctrl (contiguous)

    void* args[] = {(void*)&cls, (void*)&reg, (void*)&anc, (void*)&hist1, (void*)&ctrl,
                    (void*)&cAi, (void*)&cAk, (void*)&cBi, (void*)&cBk, (void*)&out};
    hipLaunchCooperativeKernel((void*)k_all, dim3(NBLK), dim3(256), args, 0, stream);
}

// Round 9
// 154.302 us; speedup vs baseline: 2.1352x; 2.1352x over previous
//
#include <hip/hip_runtime.h>
#include <cmath>

#define A_CNT 196416
#define C_CNT 90
#define PAIRS (A_CNT / 2)            // 98208 = 12276 * 8 pairs
#define WITERS 12276                 // wave-iterations (8 pairs per wave-iter)
#define TOPK 100u
#define CAPB 2048
#define NB_RED 1536                  // 6144 waves -> exactly ~2 iters/wave
#define NB_GAT 192

// ws layout (bytes):
//   [0, 785664)          keys[A]   (uint32 monotonic score keys; 0 = below threshold)
//   [785664, 789760)     hist1[1024] (coarse: idx 0 = zero-key, 1..565 = top16-0x3D4B)
//   [789760, 789824)     ctrl[16]: 0=binB(top16) 1=G 5=candA_cnt 6=candB_cnt 8=doneR 9=doneG
//   [789824, 790336)     candA[128]  (keys strictly above binB; count = G < 100)
//   [790336, 798528)     candB[2048] (keys with top16 == binB)
#define OFF_HIST1 785664u
#define OFF_CTRL  789760u
#define OFF_CANDA 789824u
#define OFF_CANDB 790336u

#define AGENT_LD(p)    __hip_atomic_load((p), __ATOMIC_RELAXED, __HIP_MEMORY_SCOPE_AGENT)
#define AGENT_ST(p, v) __hip_atomic_store((p), (v), __ATOMIC_RELAXED, __HIP_MEMORY_SCOPE_AGENT)

// Kernel 1: 8 lanes cooperate on one anchor-pair (720 B = 45 float4) — best
// observed structure (R5; pinned at ~44 us by harness-reset bus contention,
// structure-independent across R2/R4/R5/R6 variants). Fused tail: the LAST
// block (done-counter) runs the 1024-bin suffix-scan select and publishes
// binB/G in ctrl. Visibility: every thread's hist1 atomics complete (vmcnt)
// at the __syncthreads before t0's done-increment; the last block reads hist1
// with agent-scope loads (G16).
__global__ __launch_bounds__(256, 4) void k_reduce(const float* __restrict__ cls,
                                                   unsigned* __restrict__ keys,
                                                   unsigned* __restrict__ hist1,
                                                   unsigned* __restrict__ ctrl) {
    __shared__ unsigned lhist[576];
    __shared__ unsigned sdata[256];
    __shared__ unsigned sbin[2];
    __shared__ int sflag;
    const int t = threadIdx.x;
    for (int j = t; j < 576; j += 256) lhist[j] = 0u;
    __syncthreads();

    const int lane = t & 63;
    const int g = lane >> 3, s = lane & 7;
    const int wid = blockIdx.x * 4 + (t >> 6);
    const int nw = NB_RED * 4;
    const float4* __restrict__ cls4 = (const float4*)cls;

    for (int w = wid; w < WITERS; w += nw) {
        const int p = w * 8 + g;                     // pair index (always < PAIRS)
        const float4* __restrict__ r4 = cls4 + (size_t)p * 45;
        float m0 = -INFINITY, m1 = -INFINITY;
#pragma unroll
        for (int i = 0; i < 6; ++i) {
            const int j = s + 8 * i;                 // 45 chunks: s<5 -> 6, s>=5 -> 5
            if (j < 45) {
                float4 v = r4[j];
                float a01 = fmaxf(v.x, v.y), a23 = fmaxf(v.z, v.w);
                float all = fmaxf(a01, a23);
                if (j < 22)      m0 = fmaxf(m0, all);
                else if (j > 22) m1 = fmaxf(m1, all);
                else { m0 = fmaxf(m0, a01); m1 = fmaxf(m1, a23); }  // 88,89|90,91 split
            }
        }
#pragma unroll
        for (int d = 1; d < 8; d <<= 1) {            // reduce across the 8-lane group
            m0 = fmaxf(m0, __shfl_xor(m0, d));
            m1 = fmaxf(m1, __shfl_xor(m1, d));
        }
        if (s == 0) {
            float p0 = 1.0f / (1.0f + expf(-m0));    // sigmoid(max) == max(sigmoid)
            float p1 = 1.0f / (1.0f + expf(-m1));
            unsigned k0 = (p0 > 0.05f) ? __float_as_uint(p0) : 0u;
            unsigned k1 = (p1 > 0.05f) ? __float_as_uint(p1) : 0u;
            *(uint2*)(keys + 2 * p) = make_uint2(k0, k1);
            unsigned h0 = k0 ? (min(k0 >> 16, 0x3F80u) - 0x3D4Bu) : 0u;  // 0=zeros, 1..565
            unsigned h1 = k1 ? (min(k1 >> 16, 0x3F80u) - 0x3D4Bu) : 0u;
            atomicAdd(&lhist[h0], 1u);
            atomicAdd(&lhist[h1], 1u);
        }
    }
    __syncthreads();
    for (int j = t; j < 576; j += 256) {
        unsigned c = lhist[j];
        if (c) atomicAdd(&hist1[j], c);
    }
    __syncthreads();                                 // drains each thread's atomics (vmcnt)
    if (t == 0) sflag = (atomicAdd(&ctrl[8], 1u) == NB_RED - 1u) ? 1 : 0;
    __syncthreads();
    if (!sflag) return;

    // ---- fused k_scan (last block only; uniform branch, barriers legal) ----
    const unsigned target = TOPK;
    unsigned ssum = 0;
#pragma unroll
    for (int j = 0; j < 4; ++j) ssum += AGENT_LD(&hist1[t * 4 + j]);
    sdata[t] = ssum;
    for (int d = 1; d < 256; d <<= 1) {              // Hillis-Steele inclusive suffix scan
        __syncthreads();
        unsigned add = (t + d < 256) ? sdata[t + d] : 0u;
        __syncthreads();
        sdata[t] += add;
    }
    __syncthreads();
    {
        unsigned mysuf  = sdata[t];
        unsigned nxtsuf = (t < 255) ? sdata[t + 1] : 0u;
        if (nxtsuf < target && mysuf >= target) { sbin[0] = (unsigned)t; sbin[1] = nxtsuf; }
    }
    __syncthreads();
    const unsigned chunkB = sbin[0];
    const unsigned gAbove = sbin[1];
    unsigned v = (t < 4) ? AGENT_LD(&hist1[chunkB * 4 + t]) : 0u;
    sdata[t] = v;
    for (int d = 1; d < 256; d <<= 1) {
        __syncthreads();
        unsigned add = (t + d < 256) ? sdata[t + d] : 0u;
        __syncthreads();
        sdata[t] += add;
    }
    __syncthreads();
    {
        unsigned mysuf  = sdata[t] + gAbove;
        unsigned nxtsuf = ((t < 255) ? sdata[t + 1] : 0u) + gAbove;
        if (nxtsuf < target && mysuf >= target) {
            unsigned bin = chunkB * 4 + (unsigned)t;  // hist index: 0=zeros, 1..565
            ctrl[0] = bin ? (bin + 0x3D4Bu) : 0u;     // true top-16 bits
            ctrl[1] = nxtsuf;                         // G < 100
        }
    }
}

// Kernel 2: gather candidates (one uint4 pass over keys), then the LAST block
// runs the full ranking + argmax + box decode (fused k_final).
// candA/candB payloads use agent-scope stores; reader uses agent-scope loads.
__global__ __launch_bounds__(256) void k_gather(const float* __restrict__ cls,
                                                const float* __restrict__ reg,
                                                const float* __restrict__ anc,
                                                const unsigned* __restrict__ keys,
                                                unsigned* __restrict__ ctrl,
                                                unsigned* __restrict__ candA,
                                                unsigned* __restrict__ candB,
                                                float* __restrict__ out) {
    __shared__ unsigned sAi[128], sAk[128];
    __shared__ unsigned sBi[CAPB], sBk[CAPB];
    __shared__ unsigned sel[TOPK];
    __shared__ int sflag;
    const int t = threadIdx.x;

    const unsigned binB = ctrl[0];                   // prev kernel -> plain load ok
    const int i4 = blockIdx.x * 256 + t;
    if (i4 < A_CNT / 4) {
        uint4 k = ((const uint4*)keys)[i4];
        const unsigned base = (unsigned)(4 * i4);
#pragma unroll
        for (int j = 0; j < 4; ++j) {
            unsigned kk = (j == 0) ? k.x : (j == 1) ? k.y : (j == 2) ? k.z : k.w;
            unsigned t16 = kk >> 16;
            if (t16 > binB) {
                unsigned q = atomicAdd(&ctrl[5], 1u);
                if (q < 128u) AGENT_ST(&candA[q], base + j);
            } else if (t16 == binB) {
                unsigned q = atomicAdd(&ctrl[6], 1u);
                if (q < (unsigned)CAPB) AGENT_ST(&candB[q], base + j);
            }
        }
    }
    __syncthreads();                                 // drains this thread's stores/atomics
    if (t == 0) sflag = (atomicAdd(&ctrl[9], 1u) == (unsigned)NB_GAT - 1u) ? 1 : 0;
    __syncthreads();
    if (!sflag) return;

    // ---- fused k_final (last block only) ----
    const unsigned nA = min(AGENT_LD(&ctrl[5]), 128u);   // exact G < 100
    const unsigned nB = min(AGENT_LD(&ctrl[6]), (unsigned)CAPB);
    const unsigned need = TOPK - nA;                     // >= 1; in-bin count >= need

    if (t < (int)nA) { unsigned i = AGENT_LD(&candA[t]); sAi[t] = i; sAk[t] = keys[i]; }
    for (unsigned e = (unsigned)t; e < nB; e += 256u) {
        unsigned i = AGENT_LD(&candB[e]); sBi[e] = i; sBk[e] = keys[i];
    }
    __syncthreads();

    if (t < (int)nA) {                               // rank strictly-above candidates
        unsigned mi = sAi[t], mk = sAk[t], r = 0;
        for (unsigned j = 0; j < nA; ++j) {
            unsigned ok = sAk[j];
            if (ok > mk || (ok == mk && sAi[j] < mi)) r++;
        }
        sel[r] = mi;
    }
    for (unsigned e = (unsigned)t; e < nB; e += 256u) {  // in-bin: (key desc, idx asc)
        unsigned mi = sBi[e], mk = sBk[e], r = 0;
        for (unsigned j = 0; j < nB; ++j) {
            unsigned ok = sBk[j];
            if (ok > mk || (ok == mk && sBi[j] < mi)) r++;
        }
        if (r < need) sel[nA + r] = mi;
    }
    __syncthreads();

    if (t < (int)TOPK) {
        const unsigned a = sel[t];
        const float2* row = (const float2*)(cls + (size_t)a * C_CNT);
        float bv = -INFINITY; int bi = 0;
#pragma unroll 5
        for (int c = 0; c < 45; ++c) {               // argmax over RAW logits (sigmoid
            float2 v = row[c];                       // monotonic; strict > = first-index)
            if (v.x > bv) { bv = v.x; bi = 2 * c; }
            if (v.y > bv) { bv = v.y; bi = 2 * c + 1; }
        }
        float score = __uint_as_float(keys[a]);      // prob bits, or 0.0 if thresholded
        float x1a = anc[a * 4 + 0], y1a = anc[a * 4 + 1];
        float x2a = anc[a * 4 + 2], y2a = anc[a * 4 + 3];
        float wa = x2a - x1a, ha = y2a - y1a;
        float cxa = x1a + 0.5f * wa, cya = y1a + 0.5f * ha;
        float dx = reg[a * 4 + 0] * 0.1f, dy = reg[a * 4 + 1] * 0.1f;
        float dw = reg[a * 4 + 2] * 0.2f, dh = reg[a * 4 + 3] * 0.2f;
        float cx = cxa + dx * wa, cy = cya + dy * ha;
        float w = expf(dw) * wa, h = expf(dh) * ha;
        out[t * 4 + 0] = fmaxf(cx - 0.5f * w, 0.0f);
        out[t * 4 + 1] = fmaxf(cy - 0.5f * h, 0.0f);
        out[t * 4 + 2] = fminf(cx + 0.5f * w, 1024.0f);
        out[t * 4 + 3] = fminf(cy + 0.5f * h, 1024.0f);
        out[400 + t] = score;
        out[500 + t] = (float)bi;
    }
}

extern "C" void kernel_launch(void* const* d_in, const int* in_sizes, int n_in,
                              void* d_out, int out_size, void* d_ws, size_t ws_size,
                              hipStream_t stream) {
    const float* reg = (const float*)d_in[1];
    const float* cls = (const float*)d_in[2];
    const float* anc = (const float*)d_in[3];
    float* out = (float*)d_out;
    char* ws = (char*)d_ws;
    unsigned* keys  = (unsigned*)ws;
    unsigned* hist1 = (unsigned*)(ws + OFF_HIST1);
    unsigned* ctrl  = (unsigned*)(ws + OFF_CTRL);
    unsigned* candA = (unsigned*)(ws + OFF_CANDA);
    unsigned* candB = (unsigned*)(ws + OFF_CANDB);

    // hist1 (4 KB) + ctrl (64 B, incl. done counters) are contiguous.
    hipMemsetAsync(hist1, 0, 4096 + 64, stream);
    k_reduce<<<NB_RED, 256, 0, stream>>>(cls, keys, hist1, ctrl);
    k_gather<<<NB_GAT, 256, 0, stream>>>(cls, reg, anc, keys, ctrl, candA, candB, out);
}